// Round 3
// baseline (816.215 us; speedup 1.0000x reference)
//
#include <hip/hip_runtime.h>

constexpr int NP  = 131072;   // patches
constexpr int NB  = 128;      // bags (contiguous, 1024 patches each)
constexpr int IND = 1024;     // in dim
constexpr int HID = 512;      // hidden dim
constexpr int BK  = 32;       // K-chunk per stage
constexpr int NIT = IND / BK; // 32 iterations

typedef __bf16 bf16x8 __attribute__((ext_vector_type(8)));
typedef float  f32x4  __attribute__((ext_vector_type(4)));

typedef __attribute__((address_space(1))) const unsigned int gu32;
typedef __attribute__((address_space(3))) unsigned int       lu32;

// fp32 -> bf16 RNE
__device__ __forceinline__ unsigned short f2bf(float f) {
    unsigned int u = __float_as_uint(f);
    u += 0x7fff + ((u >> 16) & 1);
    return (unsigned short)(u >> 16);
}

// K0: W1 (1024x512 f32, k-major) -> W1T (512x1024 bf16, n-major)
__global__ __launch_bounds__(256) void k_w1t(const float* __restrict__ W1,
                                             unsigned short* __restrict__ W1T) {
    __shared__ float tile[32][33];
    const int kt = blockIdx.x;           // 32 k-tiles
    const int nt = blockIdx.y;           // 16 n-tiles
    const int tx = threadIdx.x & 31;
    const int ty = threadIdx.x >> 5;     // 0..7
#pragma unroll
    for (int i = 0; i < 4; ++i)
        tile[ty + i * 8][tx] = W1[(kt * 32 + ty + i * 8) * HID + nt * 32 + tx];
    __syncthreads();
#pragma unroll
    for (int i = 0; i < 4; ++i)
        W1T[(size_t)(nt * 32 + ty + i * 8) * IND + kt * 32 + tx] = f2bf(tile[tx][ty + i * 8]);
}

// Fused MLP: h = relu(feat@W1+b1) via bf16 MFMA, M_TILE=64, full N=512/block,
// BK=32 DOUBLE-BUFFERED (one barrier/iter: staging of tile i+1 overlaps
// compute of tile i, so HBM-A / L2-B / LDS walls max-compose instead of sum).
__global__ __launch_bounds__(512, 4) void k_fused(
    const float* __restrict__ feat, const float* __restrict__ att,
    const unsigned short* __restrict__ W1T,
    const float* __restrict__ b1, const float* __restrict__ W2,
    const float* __restrict__ b2,
    float* __restrict__ out_bag, float* __restrict__ out_pos,
    float* __restrict__ out_neg, float* __restrict__ out_net)
{
    __shared__ __align__(16) union {
        struct { unsigned short A[2][64 * BK]; unsigned short B[2][HID * BK]; } g; // 8+64 KB
        struct { float part[8][64][2]; float netsm[64][2]; } e;  // aliases A[0] / A[1]
    } sm;

    const int tid  = threadIdx.x;
    const int w    = tid >> 6;      // wave 0..7: cols [w*64, w*64+64)
    const int lane = tid & 63;
    const int quad = lane >> 4;
    const int n16  = lane & 15;
    const int row0 = blockIdx.x * 64;

    f32x4 acc[4][4];
#pragma unroll
    for (int mt = 0; mt < 4; ++mt)
#pragma unroll
        for (int t = 0; t < 4; ++t)
#pragma unroll
            for (int e = 0; e < 4; ++e) acc[mt][t][e] = 0.f;

    // A staging: thread -> row tid>>3, 4-float seg tid&7 (LDS byte off = tid*8, linear)
    const int ar = tid >> 3, as = tid & 7;
    const float* aptr = feat + (size_t)(row0 + ar) * IND + as * 4;
    const int a_off = ar * BK + as * 4;

    // B staging via global_load_lds: call j covers rows [j*128, j*128+128);
    // LDS byte off = j*8192 + tid*16 (linear = wave-uniform base + lane*16)
    const int bn = tid >> 2, bs = tid & 3;
    const unsigned short* bsrc = W1T + (size_t)bn * IND + bs * 8;
    const int b_off = bn * BK + bs * 8;

    // ---- prologue: tile 0 into buf 0, prefetch A tile 1 ----
    float4 av = *reinterpret_cast<const float4*>(aptr);
#pragma unroll
    for (int j = 0; j < 4; ++j)
        __builtin_amdgcn_global_load_lds((gu32*)(bsrc + (size_t)j * 128 * IND),
                                         (lu32*)(&sm.g.B[0][j * 128 * BK + b_off]), 16, 0, 0);
    {
        unsigned short ab[4] = { f2bf(av.x), f2bf(av.y), f2bf(av.z), f2bf(av.w) };
        *reinterpret_cast<ushort4*>(&sm.g.A[0][a_off]) = *reinterpret_cast<const ushort4*>(ab);
    }
    av = *reinterpret_cast<const float4*>(aptr + BK);
    __syncthreads();

#pragma unroll
    for (int i = 0; i < NIT; ++i) {
        const int cur = i & 1, nxt = cur ^ 1;
        if (i < NIT - 1) {
            // B tile i+1 -> other buffer (async DMA; drained by this iter's barrier,
            // overlapped with the compute below)
#pragma unroll
            for (int j = 0; j < 4; ++j)
                __builtin_amdgcn_global_load_lds(
                    (gu32*)(bsrc + (size_t)j * 128 * IND + (i + 1) * BK),
                    (lu32*)(&sm.g.B[nxt][j * 128 * BK + b_off]), 16, 0, 0);
            // A tile i+1 (prefetched last iter) -> other buffer
            unsigned short ab[4] = { f2bf(av.x), f2bf(av.y), f2bf(av.z), f2bf(av.w) };
            *reinterpret_cast<ushort4*>(&sm.g.A[nxt][a_off]) = *reinterpret_cast<const ushort4*>(ab);
            // prefetch A tile i+2 into registers (full-iteration slack for HBM latency)
            if (i < NIT - 2) av = *reinterpret_cast<const float4*>(aptr + (i + 2) * BK);
        }
        // ---- compute tile i ----
        bf16x8 afr[4], bfr[4];
#pragma unroll
        for (int mt = 0; mt < 4; ++mt)   // A[m = n16 + 16mt][k = quad*8 + j]
            afr[mt] = *reinterpret_cast<const bf16x8*>(&sm.g.A[cur][(mt * 16 + n16) * BK + quad * 8]);
#pragma unroll
        for (int t = 0; t < 4; ++t)      // B^T row n = w*64 + t*16 + n16
            bfr[t] = *reinterpret_cast<const bf16x8*>(&sm.g.B[cur][(w * 64 + t * 16 + n16) * BK + quad * 8]);
#pragma unroll
        for (int mt = 0; mt < 4; ++mt)
#pragma unroll
            for (int t = 0; t < 4; ++t)
                acc[mt][t] = __builtin_amdgcn_mfma_f32_16x16x32_bf16(afr[mt], bfr[t], acc[mt][t], 0, 0, 0);
        __syncthreads();
    }

    // ---- epilogue: logits = relu(acc + b1) @ W2 ----
    // C/D layout: col = lane&15 (in 16-tile), row = quad*4 + reg
    float lp[16][2];
#pragma unroll
    for (int i = 0; i < 16; ++i) { lp[i][0] = 0.f; lp[i][1] = 0.f; }
#pragma unroll
    for (int t = 0; t < 4; ++t) {
        int col = (w * 4 + t) * 16 + n16;
        float bias = b1[col];
        float w20 = W2[col * 2], w21 = W2[col * 2 + 1];
#pragma unroll
        for (int mt = 0; mt < 4; ++mt)
#pragma unroll
            for (int r = 0; r < 4; ++r) {
                float h = fmaxf(acc[mt][t][r] + bias, 0.f);
                lp[mt * 4 + r][0] += h * w20;
                lp[mt * 4 + r][1] += h * w21;
            }
    }
#pragma unroll
    for (int off = 8; off >= 1; off >>= 1)
#pragma unroll
        for (int i = 0; i < 16; ++i) {
            lp[i][0] += __shfl_xor(lp[i][0], off);
            lp[i][1] += __shfl_xor(lp[i][1], off);
        }
    if (n16 == 0) {
#pragma unroll
        for (int mt = 0; mt < 4; ++mt)
#pragma unroll
            for (int r = 0; r < 4; ++r) {
                sm.e.part[w][mt * 16 + quad * 4 + r][0] = lp[mt * 4 + r][0];
                sm.e.part[w][mt * 16 + quad * 4 + r][1] = lp[mt * 4 + r][1];
            }
    }
    __syncthreads();

    if (tid < 128) {
        int r = tid >> 1, j = tid & 1;
        float raw = b2[j];
#pragma unroll
        for (int ww = 0; ww < 8; ++ww) raw += sm.e.part[ww][r][j];
        int grow = row0 + r;
        float a0 = att[grow * 2], a1 = att[grow * 2 + 1];
        float pos = a0 * fmaxf(raw, 0.f);
        float neg = a1 * fmaxf(-raw, 0.f);
        float net = pos - neg;
        out_pos[grow * 2 + j] = pos;
        out_neg[grow * 2 + j] = neg;
        out_net[grow * 2 + j] = net;
        sm.e.netsm[r][j] = net;
    }
    __syncthreads();

    // all 64 rows of this block belong to one bag (64 | 1024)
    if (tid < 2) {
        float s = 0.f;
#pragma unroll 8
        for (int r = 0; r < 64; ++r) s += sm.e.netsm[r][tid];
        atomicAdd(&out_bag[(row0 >> 10) * 2 + tid], s);
    }
}

extern "C" void kernel_launch(void* const* d_in, const int* in_sizes, int n_in,
                              void* d_out, int out_size, void* d_ws, size_t ws_size,
                              hipStream_t stream) {
    const float* feat = (const float*)d_in[0];
    const float* att  = (const float*)d_in[1];
    // d_in[2] = bag_sizes: fixed 1024/bag, contiguous segments
    const float* W1   = (const float*)d_in[3];
    const float* b1   = (const float*)d_in[4];
    const float* W2   = (const float*)d_in[5];
    const float* b2   = (const float*)d_in[6];
    float* out = (float*)d_out;
    unsigned short* W1T = (unsigned short*)d_ws;   // 1 MB scratch

    hipMemsetAsync(out, 0, NB * 2 * sizeof(float), stream);
    k_w1t<<<dim3(32, 16), 256, 0, stream>>>(W1, W1T);
    k_fused<<<NP / 64, 512, 0, stream>>>(feat, att, W1T, b1, W2, b2,
                                         out,                    // bag_logits [128,2]
                                         out + 256,              // pos_evidence
                                         out + 256 + NP * 2,     // neg_evidence
                                         out + 256 + NP * 4);    // net_evidence
}

// Round 4
// 792.434 us; speedup vs baseline: 1.0300x; 1.0300x over previous
//
#include <hip/hip_runtime.h>

constexpr int NP  = 131072;   // patches
constexpr int NB  = 128;      // bags (contiguous, 1024 patches each)
constexpr int IND = 1024;     // in dim
constexpr int HID = 512;      // hidden dim
constexpr int BK  = 32;       // K-chunk per iteration
constexpr int NIT = IND / BK; // 32 iterations

typedef __bf16 bf16x8 __attribute__((ext_vector_type(8)));
typedef float  f32x4  __attribute__((ext_vector_type(4)));

// fp32 -> bf16 RNE
__device__ __forceinline__ unsigned short f2bf(float f) {
    unsigned int u = __float_as_uint(f);
    u += 0x7fff + ((u >> 16) & 1);
    return (unsigned short)(u >> 16);
}

// W1 (1024x512 f32, k-major) -> W1F bf16 in MFMA B-fragment order:
// element (n, k) -> W1F[(k>>5)*HID*32 + n*32 + (k&31)]
// so a wave's B-fragment load is one contiguous, coalesced global_load_dwordx4.
__global__ __launch_bounds__(256) void k_w1t(const float* __restrict__ W1,
                                             unsigned short* __restrict__ W1F) {
    __shared__ float tile[32][33];
    const int kt = blockIdx.x;           // 32 k-tiles
    const int nt = blockIdx.y;           // 16 n-tiles
    const int tx = threadIdx.x & 31;
    const int ty = threadIdx.x >> 5;     // 0..7
#pragma unroll
    for (int i = 0; i < 4; ++i)
        tile[ty + i * 8][tx] = W1[(kt * 32 + ty + i * 8) * HID + nt * 32 + tx];
    __syncthreads();
#pragma unroll
    for (int i = 0; i < 4; ++i) {
        int nl = ty + i * 8;
        W1F[kt * HID * 32 + (nt * 32 + nl) * 32 + tx] = f2bf(tile[tx][nl]);
    }
}

// Fused MLP: h = relu(feat@W1+b1) via bf16 MFMA (M=64, full N=512/block).
// B is register-direct from L2 (fragment-ordered W1F, no LDS, pipelined under
// MFMA with plain vmcnt waits). A goes through a 16 KB double-buffered LDS
// stage (one fp32->bf16 convert per element). One barrier per iteration.
__global__ __launch_bounds__(512, 4) void k_fused(
    const float* __restrict__ feat, const float* __restrict__ att,
    const unsigned short* __restrict__ W1F,
    const float* __restrict__ b1, const float* __restrict__ W2,
    const float* __restrict__ b2,
    float* __restrict__ out_bag, float* __restrict__ out_pos,
    float* __restrict__ out_neg, float* __restrict__ out_net)
{
    __shared__ __align__(16) union {
        unsigned short A[2][64 * BK];                            // 2 x 4 KB
        struct { float part[8][64][2]; float netsm[64][2]; } e;  // 4.5 KB (aliases A)
    } sm;

    const int tid  = threadIdx.x;
    const int w    = tid >> 6;      // wave 0..7: cols [w*64, w*64+64)
    const int lane = tid & 63;
    const int quad = lane >> 4;
    const int n16  = lane & 15;
    const int row0 = blockIdx.x * 64;

    f32x4 acc[4][4];
#pragma unroll
    for (int mt = 0; mt < 4; ++mt)
#pragma unroll
        for (int t = 0; t < 4; ++t)
#pragma unroll
            for (int e = 0; e < 4; ++e) acc[mt][t][e] = 0.f;

    // A staging: thread -> row tid>>3, float4 seg tid&7
    const int ar = tid >> 3, as = tid & 7;
    const float* aptr = feat + (size_t)(row0 + ar) * IND + as * 4;
    const int a_off = ar * BK + as * 4;

    // B fragment base: lane (w, t, quad, n16) reads W1F[i][w*64+t*16+n16][quad*8 .. +8]
    const unsigned short* bptr = W1F + (w * 64 + n16) * 32 + quad * 8;

    // ---- prologue: tile 0 staged, tile 1 in regs ----
    float4 av = *reinterpret_cast<const float4*>(aptr);
    {
        unsigned short ab[4] = { f2bf(av.x), f2bf(av.y), f2bf(av.z), f2bf(av.w) };
        *reinterpret_cast<ushort4*>(&sm.A[0][a_off]) = *reinterpret_cast<const ushort4*>(ab);
    }
    av = *reinterpret_cast<const float4*>(aptr + BK);
    __syncthreads();

#pragma unroll 2
    for (int i = 0; i < NIT; ++i) {
        const int cur = i & 1, nxt = cur ^ 1;

        // stage A tile i+1 (from regs) into the other buffer, then prefetch
        // tile i+2 EARLY so the barrier's vmcnt drain has maximal slack
        if (i < NIT - 1) {
            unsigned short ab[4] = { f2bf(av.x), f2bf(av.y), f2bf(av.z), f2bf(av.w) };
            *reinterpret_cast<ushort4*>(&sm.A[nxt][a_off]) = *reinterpret_cast<const ushort4*>(ab);
            if (i < NIT - 2) av = *reinterpret_cast<const float4*>(aptr + (i + 2) * BK);
        }

        // B fragments straight from L2 (contiguous 16 B per lane)
        bf16x8 bfr[4];
#pragma unroll
        for (int t = 0; t < 4; ++t)
            bfr[t] = *reinterpret_cast<const bf16x8*>(bptr + (size_t)i * HID * 32 + t * 512);

        // A fragments from LDS
        bf16x8 afr[4];
#pragma unroll
        for (int mt = 0; mt < 4; ++mt)
            afr[mt] = *reinterpret_cast<const bf16x8*>(&sm.A[cur][(mt * 16 + n16) * BK + quad * 8]);

#pragma unroll
        for (int mt = 0; mt < 4; ++mt)
#pragma unroll
            for (int t = 0; t < 4; ++t)
                acc[mt][t] = __builtin_amdgcn_mfma_f32_16x16x32_bf16(afr[mt], bfr[t], acc[mt][t], 0, 0, 0);

        __syncthreads();
    }

    // ---- epilogue: logits = relu(acc + b1) @ W2 ----
    // C/D layout: col = lane&15 (in 16-tile), row = quad*4 + reg
    float lp[16][2];
#pragma unroll
    for (int i = 0; i < 16; ++i) { lp[i][0] = 0.f; lp[i][1] = 0.f; }
#pragma unroll
    for (int t = 0; t < 4; ++t) {
        int col = (w * 4 + t) * 16 + n16;
        float bias = b1[col];
        float w20 = W2[col * 2], w21 = W2[col * 2 + 1];
#pragma unroll
        for (int mt = 0; mt < 4; ++mt)
#pragma unroll
            for (int r = 0; r < 4; ++r) {
                float h = fmaxf(acc[mt][t][r] + bias, 0.f);
                lp[mt * 4 + r][0] += h * w20;
                lp[mt * 4 + r][1] += h * w21;
            }
    }
#pragma unroll
    for (int off = 8; off >= 1; off >>= 1)
#pragma unroll
        for (int i = 0; i < 16; ++i) {
            lp[i][0] += __shfl_xor(lp[i][0], off);
            lp[i][1] += __shfl_xor(lp[i][1], off);
        }
    if (n16 == 0) {
#pragma unroll
        for (int mt = 0; mt < 4; ++mt)
#pragma unroll
            for (int r = 0; r < 4; ++r) {
                sm.e.part[w][mt * 16 + quad * 4 + r][0] = lp[mt * 4 + r][0];
                sm.e.part[w][mt * 16 + quad * 4 + r][1] = lp[mt * 4 + r][1];
            }
    }
    __syncthreads();

    if (tid < 128) {
        int r = tid >> 1, j = tid & 1;
        float raw = b2[j];
#pragma unroll
        for (int ww = 0; ww < 8; ++ww) raw += sm.e.part[ww][r][j];
        int grow = row0 + r;
        float a0 = att[grow * 2], a1 = att[grow * 2 + 1];
        float pos = a0 * fmaxf(raw, 0.f);
        float neg = a1 * fmaxf(-raw, 0.f);
        float net = pos - neg;
        out_pos[grow * 2 + j] = pos;
        out_neg[grow * 2 + j] = neg;
        out_net[grow * 2 + j] = net;
        sm.e.netsm[r][j] = net;
    }
    __syncthreads();

    // all 64 rows of this block belong to one bag (64 | 1024)
    if (tid < 2) {
        float s = 0.f;
#pragma unroll 8
        for (int r = 0; r < 64; ++r) s += sm.e.netsm[r][tid];
        atomicAdd(&out_bag[(row0 >> 10) * 2 + tid], s);
    }
}

extern "C" void kernel_launch(void* const* d_in, const int* in_sizes, int n_in,
                              void* d_out, int out_size, void* d_ws, size_t ws_size,
                              hipStream_t stream) {
    const float* feat = (const float*)d_in[0];
    const float* att  = (const float*)d_in[1];
    // d_in[2] = bag_sizes: fixed 1024/bag, contiguous segments
    const float* W1   = (const float*)d_in[3];
    const float* b1   = (const float*)d_in[4];
    const float* W2   = (const float*)d_in[5];
    const float* b2   = (const float*)d_in[6];
    float* out = (float*)d_out;
    unsigned short* W1F = (unsigned short*)d_ws;   // 1 MB scratch

    hipMemsetAsync(out, 0, NB * 2 * sizeof(float), stream);
    k_w1t<<<dim3(32, 16), 256, 0, stream>>>(W1, W1F);
    k_fused<<<NP / 64, 512, 0, stream>>>(feat, att, W1F, b1, W2, b2,
                                         out,                    // bag_logits [128,2]
                                         out + 256,              // pos_evidence
                                         out + 256 + NP * 2,     // neg_evidence
                                         out + 256 + NP * 4);    // net_evidence
}